// Round 12
// baseline (369.270 us; speedup 1.0000x reference)
//
#include <hip/hip_runtime.h>

#define Bb 64
#define Nn 8192
#define Ff 32
#define Gg 32
#define G3 (Gg*Gg*Gg)          // 32768
#define NATOM (Bb*Nn)          // 524288

// ---------------- ws layout ----------------
// [0, 8448)   slabStart[64][33] u32: batch-local sorted-offset of each ix-slab
// [8448, +2MB) atomIdx[NATOM] u32: (spatial15 << 13) | local_atom_id13, bin-sorted
static const size_t WS_SLAB = 0;
static const size_t WS_AIDX = 8448;
static const size_t WS_NEED = WS_AIDX + (size_t)NATOM * 4;

// One block per batch (1024 threads, 8 atoms/thread): fp64 centroid ->
// two-pass LDS histogram (u32[16384] = 64 KB) -> in-LDS scan -> slab offsets
// + LDS-atomic placement of packed (spatial|id) into atomIdx.
__global__ void __launch_bounds__(1024) fused_sort_kernel(const float* __restrict__ coords,
                                                          unsigned* __restrict__ slabStart,
                                                          unsigned* __restrict__ atomIdx) {
    __shared__ unsigned long long lds8[8192];      // 64 KB, 8B-aligned
    unsigned* hist = (unsigned*)lds8;              // [16384] bins per pass
    double*   dred = (double*)lds8;                // [1024*3] centroid reduction

    const int b = blockIdx.x;
    const int t = threadIdx.x;
    const int wave = t >> 6, lane = t & 63;

    if (t == 0) slabStart[b * 33 + 32] = Nn;       // sentinel: slab 32 end

    float ax[8], ay[8], az[8];
    const float* cb = coords + (size_t)b * Nn * 3;
    #pragma unroll
    for (int i = 0; i < 8; ++i) {
        const int n = t + 1024 * i;
        ax[i] = cb[n * 3 + 0]; ay[i] = cb[n * 3 + 1]; az[i] = cb[n * 3 + 2];
    }

    double sx = 0.0, sy = 0.0, sz = 0.0;
    #pragma unroll
    for (int i = 0; i < 8; ++i) { sx += (double)ax[i]; sy += (double)ay[i]; sz += (double)az[i]; }
    dred[t * 3 + 0] = sx; dred[t * 3 + 1] = sy; dred[t * 3 + 2] = sz;
    __syncthreads();
    for (int s = 512; s > 0; s >>= 1) {
        if (t < s) {
            dred[t * 3 + 0] += dred[(t + s) * 3 + 0];
            dred[t * 3 + 1] += dred[(t + s) * 3 + 1];
            dred[t * 3 + 2] += dred[(t + s) * 3 + 2];
        }
        __syncthreads();
    }
    const float cx = (float)(dred[0] * (1.0 / Nn));
    const float cy = (float)(dred[1] * (1.0 / Nn));
    const float cz = (float)(dred[2] * (1.0 / Nn));
    __syncthreads();

    unsigned bin[8];
    #pragma unroll
    for (int i = 0; i < 8; ++i) {
        const int ix = min(max((int)((ax[i] - cx) + 16.0f), 0), Gg - 1);
        const int iy = min(max((int)((ay[i] - cy) + 16.0f), 0), Gg - 1);
        const int iz = min(max((int)((az[i] - cz) + 16.0f), 0), Gg - 1);
        bin[i] = ((unsigned)ix << 10) | ((unsigned)iy << 5) | (unsigned)iz;
    }

    unsigned passbase = 0;
    for (int pass = 0; pass < 2; ++pass) {
        const unsigned lo = (unsigned)pass << 14;
        #pragma unroll
        for (int j = 0; j < 16; ++j) hist[t + 1024 * j] = 0u;
        __syncthreads();
        #pragma unroll
        for (int i = 0; i < 8; ++i)
            if ((bin[i] >> 14) == (unsigned)pass) atomicAdd(&hist[bin[i] & 16383u], 1u);
        __syncthreads();

        const int w0 = t * 16;
        unsigned s = 0;
        #pragma unroll
        for (int j = 0; j < 16; ++j) s += hist[w0 + j] & 0xFFFFu;
        unsigned incl = s;
        #pragma unroll
        for (int d = 1; d < 64; d <<= 1) {
            const unsigned u = __shfl_up(incl, d);
            if (lane >= d) incl += u;
        }
        if (lane == 63) hist[wave] = (hist[wave] & 0xFFFFu) | (incl << 16);
        __syncthreads();
        unsigned wbase = 0, tot = 0;
        #pragma unroll
        for (int w = 0; w < 16; ++w) {
            const unsigned wt = hist[w] >> 16;
            if (w < wave) wbase += wt;
            tot += wt;
        }
        unsigned running = passbase + wbase + (incl - s);
        __syncthreads();
        // slab boundary: bins at (bin & 1023)==0 live at threads t%64==0, j==0
        if ((t & 63) == 0)
            slabStart[b * 33 + ((lo + (unsigned)w0) >> 10)] = running;
        #pragma unroll
        for (int j = 0; j < 16; ++j) {
            const unsigned c = hist[w0 + j] & 0xFFFFu;
            hist[w0 + j] = running;                 // start offset for placement
            running += c;
        }
        __syncthreads();
        #pragma unroll
        for (int i = 0; i < 8; ++i)
            if ((bin[i] >> 14) == (unsigned)pass) {
                const unsigned pos = atomicAdd(&hist[bin[i] & 16383u], 1u);
                atomIdx[(size_t)b * Nn + pos] = (bin[i] << 13) | (unsigned)(t + 1024 * i);
            }
        __syncthreads();
        passbase = tot;
    }
}

// One block per (b, ix) slab: 128 KiB LDS = the slab's full output tile
// [32 f][1024 cells]. Stream the slab's sorted atoms: random 128 B feature
// read (1 MB/batch -> L2), W*f+b via wave-uniform s_load + v_fmac,
// ds_add_f32 scatter into LDS, then one coalesced dwordx4 write-out.
__global__ void __launch_bounds__(1024) fused_scatter_kernel(const unsigned* __restrict__ slabStart,
                                                             const unsigned* __restrict__ atomIdx,
                                                             const float* __restrict__ features,
                                                             const float* __restrict__ W,
                                                             const float* __restrict__ bias,
                                                             float* __restrict__ out) {
    __shared__ float ldsf[Ff * 1024];              // 128 KiB: [f][cell]
    const int b  = blockIdx.x >> 5;
    const int ix = blockIdx.x & 31;
    const int t  = threadIdx.x;

    // zero the tile: 8 float4 per thread
    float4* l4 = reinterpret_cast<float4*>(ldsf);
    #pragma unroll
    for (int i = 0; i < 8; ++i) l4[t + 1024 * i] = make_float4(0.f, 0.f, 0.f, 0.f);
    __syncthreads();

    const unsigned s0 = slabStart[b * 33 + ix];
    const unsigned s1 = slabStart[b * 33 + ix + 1];
    const unsigned count = s1 - s0;
    const unsigned* slot = atomIdx + (size_t)b * Nn + s0;
    const float* fb = features + (size_t)b * Nn * Ff;

    for (unsigned idx = t; idx < count; idx += 1024) {
        const unsigned v = slot[idx];
        const unsigned cell = (v >> 13) & 1023u;   // iy*32+iz
        const float4* f4 = reinterpret_cast<const float4*>(fb + (size_t)(v & 8191u) * Ff);
        float ft[Ff];
        #pragma unroll
        for (int q = 0; q < 8; ++q) {
            const float4 x = f4[q];
            ft[4 * q + 0] = x.x; ft[4 * q + 1] = x.y;
            ft[4 * q + 2] = x.z; ft[4 * q + 3] = x.w;
        }
        #pragma unroll
        for (int f = 0; f < Ff; f += 4) {
            float v0 = bias[f + 0], v1 = bias[f + 1], v2 = bias[f + 2], v3 = bias[f + 3];
            #pragma unroll
            for (int j = 0; j < Ff; ++j) {
                const float x = ft[j];
                v0 += W[(f + 0) * Ff + j] * x;     // uniform -> s_load, v_fmac v,s,v
                v1 += W[(f + 1) * Ff + j] * x;
                v2 += W[(f + 2) * Ff + j] * x;
                v3 += W[(f + 3) * Ff + j] * x;
            }
            atomicAdd(&ldsf[(f + 0) * 1024 + cell], v0);   // ds_add_f32
            atomicAdd(&ldsf[(f + 1) * 1024 + cell], v1);
            atomicAdd(&ldsf[(f + 2) * 1024 + cell], v2);
            atomicAdd(&ldsf[(f + 3) * 1024 + cell], v3);
        }
    }
    __syncthreads();

    // write-out: thread t -> plane f = t>>5, covers cells 4*((t&31)+32i)
    const int f = t >> 5, g = t & 31;
    float* op = out + ((size_t)(b * Ff + f) * G3) + ix * 1024;
    #pragma unroll
    for (int i = 0; i < 8; ++i) {
        const int c4 = g + 32 * i;
        const float4 vv = *reinterpret_cast<const float4*>(&ldsf[f * 1024 + 4 * c4]);
        *reinterpret_cast<float4*>(op + 4 * c4) = vv;
    }
}

// ---------- fallback (atomic path) if ws is too small ----------
__global__ void __launch_bounds__(256) centers_kernel(const float* __restrict__ coords,
                                                      float* __restrict__ centers) {
    const int b = blockIdx.x;
    const int t = threadIdx.x;
    double sx = 0.0, sy = 0.0, sz = 0.0;
    const float* cb = coords + (size_t)b * Nn * 3;
    for (int n = t; n < Nn; n += 256) {
        sx += (double)cb[n * 3 + 0];
        sy += (double)cb[n * 3 + 1];
        sz += (double)cb[n * 3 + 2];
    }
    __shared__ double red[256][3];
    red[t][0] = sx; red[t][1] = sy; red[t][2] = sz;
    __syncthreads();
    for (int s = 128; s > 0; s >>= 1) {
        if (t < s) {
            red[t][0] += red[t + s][0];
            red[t][1] += red[t + s][1];
            red[t][2] += red[t + s][2];
        }
        __syncthreads();
    }
    if (t < 3) centers[b * 3 + t] = (float)(red[0][t] * (1.0 / Nn));
}

__global__ void __launch_bounds__(256) scatter_kernel(const float* __restrict__ coords,
                                                      const float* __restrict__ features,
                                                      const float* __restrict__ W,
                                                      const float* __restrict__ bias,
                                                      const float* __restrict__ centers,
                                                      float* __restrict__ out) {
    __shared__ float Wl[Ff * Ff];
    __shared__ float bl[Ff];
    for (int i = threadIdx.x; i < Ff * Ff; i += 256) Wl[i] = W[i];
    if (threadIdx.x < Ff) bl[threadIdx.x] = bias[threadIdx.x];
    __syncthreads();
    const int atom = blockIdx.x * 256 + threadIdx.x;
    const int b = atom >> 13;
    const float cx = centers[b * 3 + 0];
    const float cy = centers[b * 3 + 1];
    const float cz = centers[b * 3 + 2];
    const float* cp = coords + (size_t)atom * 3;
    const int ix = min(max((int)((cp[0] - cx) + 16.0f), 0), Gg - 1);
    const int iy = min(max((int)((cp[1] - cy) + 16.0f), 0), Gg - 1);
    const int iz = min(max((int)((cp[2] - cz) + 16.0f), 0), Gg - 1);
    const int spatial = ix * (Gg * Gg) + iy * Gg + iz;
    float* outb = out + (size_t)b * Ff * G3 + spatial;
    float ft[Ff];
    const float4* f4 = reinterpret_cast<const float4*>(features + (size_t)atom * Ff);
    #pragma unroll
    for (int q = 0; q < 8; ++q) {
        const float4 v = f4[q];
        ft[4 * q + 0] = v.x; ft[4 * q + 1] = v.y;
        ft[4 * q + 2] = v.z; ft[4 * q + 3] = v.w;
    }
    #pragma unroll 4
    for (int fo = 0; fo < Ff; ++fo) {
        float a2 = bl[fo];
        #pragma unroll
        for (int j = 0; j < Ff; ++j) a2 += Wl[fo * Ff + j] * ft[j];
        atomicAdd(outb + (size_t)fo * G3, a2);
    }
}

extern "C" void kernel_launch(void* const* d_in, const int* in_sizes, int n_in,
                              void* d_out, int out_size, void* d_ws, size_t ws_size,
                              hipStream_t stream) {
    const float* coords   = (const float*)d_in[0];
    const float* features = (const float*)d_in[1];
    const float* W        = (const float*)d_in[2];
    const float* bias     = (const float*)d_in[3];
    float* out = (float*)d_out;

    char* ws = (char*)d_ws;

    if (ws_size < WS_NEED) {
        float* centers = (float*)ws;
        hipMemsetAsync(d_out, 0, (size_t)out_size * sizeof(float), stream);
        centers_kernel<<<Bb, 256, 0, stream>>>(coords, centers);
        scatter_kernel<<<(NATOM) / 256, 256, 0, stream>>>(coords, features, W, bias, centers, out);
        return;
    }

    unsigned* slabStart = (unsigned*)(ws + WS_SLAB);
    unsigned* atomIdx   = (unsigned*)(ws + WS_AIDX);

    fused_sort_kernel<<<Bb, 1024, 0, stream>>>(coords, slabStart, atomIdx);
    fused_scatter_kernel<<<Bb * 32, 1024, 0, stream>>>(slabStart, atomIdx, features, W, bias, out);
}

// Round 13
// 232.196 us; speedup vs baseline: 1.5903x; 1.5903x over previous
//
#include <hip/hip_runtime.h>

#define Bb 64
#define Nn 8192
#define Ff 32
#define Gg 32
#define G3 (Gg*Gg*Gg)          // 32768
#define NATOM (Bb*Nn)          // 524288

// ---------------- ws layout ----------------
// [0, 16644)   slabStart[64][65] u32: batch-local sorted offset of each 512-bin
//              half-slab (b, ix, iy>=16); [b][64] = Nn sentinel
// [16896, +2MB) atomIdx[NATOM] u32: (bin15 << 13) | local_atom_id13, bin-sorted
static const size_t WS_SLAB = 0;
static const size_t WS_AIDX = 16896;
static const size_t WS_NEED = WS_AIDX + (size_t)NATOM * 4;

// One block per batch (1024 threads, 8 atoms/thread): fp64 centroid ->
// two-pass LDS histogram (u32[16384] = 64 KB) -> in-LDS scan -> half-slab
// offsets + LDS-atomic placement of packed (bin|id) into atomIdx.
__global__ void __launch_bounds__(1024) fused_sort_kernel(const float* __restrict__ coords,
                                                          unsigned* __restrict__ slabStart,
                                                          unsigned* __restrict__ atomIdx) {
    __shared__ unsigned long long lds8[8192];      // 64 KB, 8B-aligned
    unsigned* hist = (unsigned*)lds8;              // [16384] bins per pass
    double*   dred = (double*)lds8;                // [1024*3] centroid reduction

    const int b = blockIdx.x;
    const int t = threadIdx.x;
    const int wave = t >> 6, lane = t & 63;

    if (t == 0) slabStart[b * 65 + 64] = Nn;       // sentinel

    float ax[8], ay[8], az[8];
    const float* cb = coords + (size_t)b * Nn * 3;
    #pragma unroll
    for (int i = 0; i < 8; ++i) {
        const int n = t + 1024 * i;
        ax[i] = cb[n * 3 + 0]; ay[i] = cb[n * 3 + 1]; az[i] = cb[n * 3 + 2];
    }

    double sx = 0.0, sy = 0.0, sz = 0.0;
    #pragma unroll
    for (int i = 0; i < 8; ++i) { sx += (double)ax[i]; sy += (double)ay[i]; sz += (double)az[i]; }
    dred[t * 3 + 0] = sx; dred[t * 3 + 1] = sy; dred[t * 3 + 2] = sz;
    __syncthreads();
    for (int s = 512; s > 0; s >>= 1) {
        if (t < s) {
            dred[t * 3 + 0] += dred[(t + s) * 3 + 0];
            dred[t * 3 + 1] += dred[(t + s) * 3 + 1];
            dred[t * 3 + 2] += dred[(t + s) * 3 + 2];
        }
        __syncthreads();
    }
    const float cx = (float)(dred[0] * (1.0 / Nn));
    const float cy = (float)(dred[1] * (1.0 / Nn));
    const float cz = (float)(dred[2] * (1.0 / Nn));
    __syncthreads();

    unsigned bin[8];
    #pragma unroll
    for (int i = 0; i < 8; ++i) {
        const int ix = min(max((int)((ax[i] - cx) + 16.0f), 0), Gg - 1);
        const int iy = min(max((int)((ay[i] - cy) + 16.0f), 0), Gg - 1);
        const int iz = min(max((int)((az[i] - cz) + 16.0f), 0), Gg - 1);
        bin[i] = ((unsigned)ix << 10) | ((unsigned)iy << 5) | (unsigned)iz;
    }

    unsigned passbase = 0;
    for (int pass = 0; pass < 2; ++pass) {
        const unsigned lo = (unsigned)pass << 14;
        #pragma unroll
        for (int j = 0; j < 16; ++j) hist[t + 1024 * j] = 0u;
        __syncthreads();
        #pragma unroll
        for (int i = 0; i < 8; ++i)
            if ((bin[i] >> 14) == (unsigned)pass) atomicAdd(&hist[bin[i] & 16383u], 1u);
        __syncthreads();

        const int w0 = t * 16;
        unsigned s = 0;
        #pragma unroll
        for (int j = 0; j < 16; ++j) s += hist[w0 + j] & 0xFFFFu;
        unsigned incl = s;
        #pragma unroll
        for (int d = 1; d < 64; d <<= 1) {
            const unsigned u = __shfl_up(incl, d);
            if (lane >= d) incl += u;
        }
        if (lane == 63) hist[wave] = (hist[wave] & 0xFFFFu) | (incl << 16);
        __syncthreads();
        unsigned wbase = 0, tot = 0;
        #pragma unroll
        for (int w = 0; w < 16; ++w) {
            const unsigned wt = hist[w] >> 16;
            if (w < wave) wbase += wt;
            tot += wt;
        }
        unsigned running = passbase + wbase + (incl - s);
        __syncthreads();
        // half-slab boundary: bins at (bin & 511)==0 live at threads t%32==0
        if ((t & 31) == 0)
            slabStart[b * 65 + ((lo + (unsigned)w0) >> 9)] = running;
        #pragma unroll
        for (int j = 0; j < 16; ++j) {
            const unsigned c = hist[w0 + j] & 0xFFFFu;
            hist[w0 + j] = running;                 // start offset for placement
            running += c;
        }
        __syncthreads();
        #pragma unroll
        for (int i = 0; i < 8; ++i)
            if ((bin[i] >> 14) == (unsigned)pass) {
                const unsigned pos = atomicAdd(&hist[bin[i] & 16383u], 1u);
                atomIdx[(size_t)b * Nn + pos] = (bin[i] << 13) | (unsigned)(t + 1024 * i);
            }
        __syncthreads();
        passbase = tot;
    }
}

// One block per half-slab (b, ix, iy-half): 66 KiB LDS = raw feature sums
// [32][512] + count[512]. Atom phase: 33 ds_add of RAW features (no matvec).
// Write phase: per-CELL matvec, fully lane-packed, k*bias + W*sum (k=0 -> 0),
// coalesced plane stores. 2 blocks/CU (66 KiB of 160) -> phases overlap.
__global__ void __launch_bounds__(512) fused_scatter_kernel(const unsigned* __restrict__ slabStart,
                                                            const unsigned* __restrict__ atomIdx,
                                                            const float* __restrict__ features,
                                                            const float* __restrict__ W,
                                                            const float* __restrict__ bias,
                                                            float* __restrict__ out) {
    __shared__ float ldsf[33 * 512];               // 66 KiB: [f][cell], cnt at f=32
    const int b = blockIdx.x >> 6;
    const int h = blockIdx.x & 63;                 // ix*2 + (iy>=16)
    const int t = threadIdx.x;

    float4* l4 = reinterpret_cast<float4*>(ldsf);
    for (int i = t; i < (33 * 512) / 4; i += 512) l4[i] = make_float4(0.f, 0.f, 0.f, 0.f);
    __syncthreads();

    const unsigned s0 = slabStart[b * 65 + h];
    const unsigned s1 = slabStart[b * 65 + h + 1];
    const float* fb = features + (size_t)b * Nn * Ff;

    for (unsigned idx = s0 + t; idx < s1; idx += 512) {
        const unsigned v = atomIdx[(size_t)b * Nn + idx];
        const unsigned cell = (v >> 13) & 511u;    // bin % 512
        const float4* f4 = reinterpret_cast<const float4*>(fb + (size_t)(v & 8191u) * Ff);
        #pragma unroll
        for (int q = 0; q < 8; ++q) {
            const float4 x = f4[q];
            atomicAdd(&ldsf[(4 * q + 0) * 512 + cell], x.x);   // ds_add_f32
            atomicAdd(&ldsf[(4 * q + 1) * 512 + cell], x.y);
            atomicAdd(&ldsf[(4 * q + 2) * 512 + cell], x.z);
            atomicAdd(&ldsf[(4 * q + 3) * 512 + cell], x.w);
        }
        atomicAdd(&ldsf[32 * 512 + cell], 1.0f);
    }
    __syncthreads();

    // per-cell matvec + write: thread t <-> cell t
    const float kf = ldsf[32 * 512 + t];
    float* op = out + (size_t)b * Ff * G3 + h * 512 + t;
    if (!__any(kf != 0.0f)) {                      // whole wave empty: zeros
        #pragma unroll
        for (int f = 0; f < Ff; ++f) op[(size_t)f * G3] = 0.0f;
        return;
    }
    float sums[Ff];
    #pragma unroll
    for (int j = 0; j < Ff; ++j) sums[j] = ldsf[j * 512 + t];
    #pragma unroll
    for (int f = 0; f < Ff; f += 4) {              // 4 independent FMA chains
        float v0 = kf * bias[f + 0];
        float v1 = kf * bias[f + 1];
        float v2 = kf * bias[f + 2];
        float v3 = kf * bias[f + 3];
        #pragma unroll
        for (int j = 0; j < Ff; ++j) {
            const float x = sums[j];
            v0 += W[(f + 0) * Ff + j] * x;         // uniform -> s_load, v_fmac v,s,v
            v1 += W[(f + 1) * Ff + j] * x;
            v2 += W[(f + 2) * Ff + j] * x;
            v3 += W[(f + 3) * Ff + j] * x;
        }
        op[(size_t)(f + 0) * G3] = v0;
        op[(size_t)(f + 1) * G3] = v1;
        op[(size_t)(f + 2) * G3] = v2;
        op[(size_t)(f + 3) * G3] = v3;
    }
}

// ---------- fallback (atomic path) if ws is too small ----------
__global__ void __launch_bounds__(256) centers_kernel(const float* __restrict__ coords,
                                                      float* __restrict__ centers) {
    const int b = blockIdx.x;
    const int t = threadIdx.x;
    double sx = 0.0, sy = 0.0, sz = 0.0;
    const float* cb = coords + (size_t)b * Nn * 3;
    for (int n = t; n < Nn; n += 256) {
        sx += (double)cb[n * 3 + 0];
        sy += (double)cb[n * 3 + 1];
        sz += (double)cb[n * 3 + 2];
    }
    __shared__ double red[256][3];
    red[t][0] = sx; red[t][1] = sy; red[t][2] = sz;
    __syncthreads();
    for (int s = 128; s > 0; s >>= 1) {
        if (t < s) {
            red[t][0] += red[t + s][0];
            red[t][1] += red[t + s][1];
            red[t][2] += red[t + s][2];
        }
        __syncthreads();
    }
    if (t < 3) centers[b * 3 + t] = (float)(red[0][t] * (1.0 / Nn));
}

__global__ void __launch_bounds__(256) scatter_kernel(const float* __restrict__ coords,
                                                      const float* __restrict__ features,
                                                      const float* __restrict__ W,
                                                      const float* __restrict__ bias,
                                                      const float* __restrict__ centers,
                                                      float* __restrict__ out) {
    __shared__ float Wl[Ff * Ff];
    __shared__ float bl[Ff];
    for (int i = threadIdx.x; i < Ff * Ff; i += 256) Wl[i] = W[i];
    if (threadIdx.x < Ff) bl[threadIdx.x] = bias[threadIdx.x];
    __syncthreads();
    const int atom = blockIdx.x * 256 + threadIdx.x;
    const int b = atom >> 13;
    const float cx = centers[b * 3 + 0];
    const float cy = centers[b * 3 + 1];
    const float cz = centers[b * 3 + 2];
    const float* cp = coords + (size_t)atom * 3;
    const int ix = min(max((int)((cp[0] - cx) + 16.0f), 0), Gg - 1);
    const int iy = min(max((int)((cp[1] - cy) + 16.0f), 0), Gg - 1);
    const int iz = min(max((int)((cp[2] - cz) + 16.0f), 0), Gg - 1);
    const int spatial = ix * (Gg * Gg) + iy * Gg + iz;
    float* outb = out + (size_t)b * Ff * G3 + spatial;
    float ft[Ff];
    const float4* f4 = reinterpret_cast<const float4*>(features + (size_t)atom * Ff);
    #pragma unroll
    for (int q = 0; q < 8; ++q) {
        const float4 v = f4[q];
        ft[4 * q + 0] = v.x; ft[4 * q + 1] = v.y;
        ft[4 * q + 2] = v.z; ft[4 * q + 3] = v.w;
    }
    #pragma unroll 4
    for (int fo = 0; fo < Ff; ++fo) {
        float a2 = bl[fo];
        #pragma unroll
        for (int j = 0; j < Ff; ++j) a2 += Wl[fo * Ff + j] * ft[j];
        atomicAdd(outb + (size_t)fo * G3, a2);
    }
}

extern "C" void kernel_launch(void* const* d_in, const int* in_sizes, int n_in,
                              void* d_out, int out_size, void* d_ws, size_t ws_size,
                              hipStream_t stream) {
    const float* coords   = (const float*)d_in[0];
    const float* features = (const float*)d_in[1];
    const float* W        = (const float*)d_in[2];
    const float* bias     = (const float*)d_in[3];
    float* out = (float*)d_out;

    char* ws = (char*)d_ws;

    if (ws_size < WS_NEED) {
        float* centers = (float*)ws;
        hipMemsetAsync(d_out, 0, (size_t)out_size * sizeof(float), stream);
        centers_kernel<<<Bb, 256, 0, stream>>>(coords, centers);
        scatter_kernel<<<(NATOM) / 256, 256, 0, stream>>>(coords, features, W, bias, centers, out);
        return;
    }

    unsigned* slabStart = (unsigned*)(ws + WS_SLAB);
    unsigned* atomIdx   = (unsigned*)(ws + WS_AIDX);

    fused_sort_kernel<<<Bb, 1024, 0, stream>>>(coords, slabStart, atomIdx);
    fused_scatter_kernel<<<Bb * 64, 512, 0, stream>>>(slabStart, atomIdx, features, W, bias, out);
}

// Round 14
// 159.797 us; speedup vs baseline: 2.3109x; 1.4531x over previous
//
#include <hip/hip_runtime.h>

#define Bb 64
#define Nn 8192
#define Ff 32
#define Gg 32
#define G3 (Gg*Gg*Gg)          // 32768
#define NATOM (Bb*Nn)          // 524288
#define NBINS (Bb*G3)          // 2^21

// ---------------- ws layout ----------------
// [0,1024)        centers (fallback only)
// [1024, +8MB)    meta[NBINS] u32: (end_local<<16)|cnt   (end,cnt <= 8192)
// [+2MB)          atomIdx[NATOM] u32 (global atom id, bin-sorted)
static const size_t WS_CENTERS = 0;
static const size_t WS_META    = 1024;
static const size_t WS_AIDX    = WS_META + (size_t)NBINS * 4;
static const size_t WS_NEED    = WS_AIDX + (size_t)NATOM * 4;

// One block per batch (1024 threads, 8 atoms/thread): fp64 centroid ->
// two-pass LDS histogram -> in-LDS scan -> meta + LDS-atomic placement.
// (byte-for-byte the R9 version that passed at 145 us)
__global__ void __launch_bounds__(1024) fused_sort_kernel(const float* __restrict__ coords,
                                                          unsigned* __restrict__ meta,
                                                          unsigned* __restrict__ atomIdx) {
    __shared__ unsigned long long lds8[8192];      // 64 KB, 8B-aligned
    unsigned* hist = (unsigned*)lds8;              // [16384] bins per pass
    double*   dred = (double*)lds8;                // [1024*3] centroid reduction

    const int b = blockIdx.x;
    const int t = threadIdx.x;
    const int wave = t >> 6, lane = t & 63;

    float ax[8], ay[8], az[8];
    const float* cb = coords + (size_t)b * Nn * 3;
    #pragma unroll
    for (int i = 0; i < 8; ++i) {
        const int n = t + 1024 * i;
        ax[i] = cb[n * 3 + 0]; ay[i] = cb[n * 3 + 1]; az[i] = cb[n * 3 + 2];
    }

    double sx = 0.0, sy = 0.0, sz = 0.0;
    #pragma unroll
    for (int i = 0; i < 8; ++i) { sx += (double)ax[i]; sy += (double)ay[i]; sz += (double)az[i]; }
    dred[t * 3 + 0] = sx; dred[t * 3 + 1] = sy; dred[t * 3 + 2] = sz;
    __syncthreads();
    for (int s = 512; s > 0; s >>= 1) {
        if (t < s) {
            dred[t * 3 + 0] += dred[(t + s) * 3 + 0];
            dred[t * 3 + 1] += dred[(t + s) * 3 + 1];
            dred[t * 3 + 2] += dred[(t + s) * 3 + 2];
        }
        __syncthreads();
    }
    const float cx = (float)(dred[0] * (1.0 / Nn));
    const float cy = (float)(dred[1] * (1.0 / Nn));
    const float cz = (float)(dred[2] * (1.0 / Nn));
    __syncthreads();

    unsigned bin[8];
    #pragma unroll
    for (int i = 0; i < 8; ++i) {
        const int ix = min(max((int)((ax[i] - cx) + 16.0f), 0), Gg - 1);
        const int iy = min(max((int)((ay[i] - cy) + 16.0f), 0), Gg - 1);
        const int iz = min(max((int)((az[i] - cz) + 16.0f), 0), Gg - 1);
        bin[i] = ((unsigned)ix << 10) | ((unsigned)iy << 5) | (unsigned)iz;
    }

    unsigned passbase = 0;
    for (int pass = 0; pass < 2; ++pass) {
        const unsigned lo = (unsigned)pass << 14;
        #pragma unroll
        for (int j = 0; j < 16; ++j) hist[t + 1024 * j] = 0u;
        __syncthreads();
        #pragma unroll
        for (int i = 0; i < 8; ++i)
            if ((bin[i] >> 14) == (unsigned)pass) atomicAdd(&hist[bin[i] & 16383u], 1u);
        __syncthreads();

        const int w0 = t * 16;
        unsigned s = 0;
        #pragma unroll
        for (int j = 0; j < 16; ++j) s += hist[w0 + j] & 0xFFFFu;
        unsigned incl = s;
        #pragma unroll
        for (int d = 1; d < 64; d <<= 1) {
            const unsigned u = __shfl_up(incl, d);
            if (lane >= d) incl += u;
        }
        if (lane == 63) hist[wave] = (hist[wave] & 0xFFFFu) | (incl << 16);
        __syncthreads();
        unsigned wbase = 0, tot = 0;
        #pragma unroll
        for (int w = 0; w < 16; ++w) {
            const unsigned wt = hist[w] >> 16;
            if (w < wave) wbase += wt;
            tot += wt;
        }
        unsigned running = passbase + wbase + (incl - s);
        __syncthreads();
        unsigned* mrow = meta + (size_t)b * 32768 + lo;
        #pragma unroll
        for (int j = 0; j < 16; ++j) {
            const unsigned c = hist[w0 + j] & 0xFFFFu;
            hist[w0 + j] = running;
            mrow[w0 + j] = ((running + c) << 16) | c;
            running += c;
        }
        __syncthreads();
        #pragma unroll
        for (int i = 0; i < 8; ++i)
            if ((bin[i] >> 14) == (unsigned)pass) {
                const unsigned pos = atomicAdd(&hist[bin[i] & 16383u], 1u);
                atomIdx[(size_t)b * Nn + pos] = (unsigned)(b * Nn) + (unsigned)(t + 1024 * i);
            }
        __syncthreads();
        passbase = tot;
    }
}

// One thread per output cell (R9 accumulate + matvec, unchanged) BUT the
// write-out goes through a per-wave 8 KB LDS tile [32 f][64 cells] so the
// 256 MB output is stored as dwordx4 (16 B/lane, 8 store instrs/thread)
// instead of 32 scalar 4 B stores (G13: scalar stores ~2-2.5x slower).
__global__ void __launch_bounds__(256) gather_kernel(const unsigned* __restrict__ meta,
                                                     const unsigned* __restrict__ atomIdx,
                                                     const float* __restrict__ features,
                                                     const float* __restrict__ W,
                                                     const float* __restrict__ bias,
                                                     float* __restrict__ out) {
    __shared__ float tile[4][Ff * 64];             // 32 KB: per-wave [f][cell]
    const int b = blockIdx.x >> 7;                 // 128 chunks of 256 cells
    const int spatial0 = (blockIdx.x & 127) << 8;
    const int t = threadIdx.x, wave = t >> 6, lane = t & 63;
    const int spatial = spatial0 + t;
    const unsigned m = meta[((size_t)b << 15) + (unsigned)spatial];
    const unsigned k = m & 0xFFFFu;
    float* wt = tile[wave];

    if (!__any((int)k)) {
        // whole wave empty: zero the tile (8 x ds_write_b128)
        float4* wt4 = reinterpret_cast<float4*>(wt);
        #pragma unroll
        for (int i = 0; i < 8; ++i) wt4[lane + 64 * i] = make_float4(0.f, 0.f, 0.f, 0.f);
    } else {
        const unsigned start = ((unsigned)b << 13) + (m >> 16) - k;
        float acc[Ff];
        #pragma unroll
        for (int j = 0; j < Ff; ++j) acc[j] = 0.0f;
        for (unsigned i = 0; i < k; ++i) {
            const unsigned a = atomIdx[start + i];
            const float4* f4 = reinterpret_cast<const float4*>(features + (size_t)a * Ff);
            #pragma unroll
            for (int q = 0; q < 8; ++q) {
                const float4 v = f4[q];
                acc[4 * q + 0] += v.x; acc[4 * q + 1] += v.y;
                acc[4 * q + 2] += v.z; acc[4 * q + 3] += v.w;
            }
        }
        const float kf = (float)k;
        #pragma unroll
        for (int f = 0; f < Ff; f += 4) {          // 4 independent FMA chains
            float v0 = kf * bias[f + 0];
            float v1 = kf * bias[f + 1];
            float v2 = kf * bias[f + 2];
            float v3 = kf * bias[f + 3];
            #pragma unroll
            for (int j = 0; j < Ff; ++j) {
                const float a = acc[j];
                v0 += W[(f + 0) * Ff + j] * a;     // uniform -> s_load, v_fmac v,s,v
                v1 += W[(f + 1) * Ff + j] * a;
                v2 += W[(f + 2) * Ff + j] * a;
                v3 += W[(f + 3) * Ff + j] * a;
            }
            // lanes write consecutive 4B of plane f -> 2 lanes/bank, free
            wt[(f + 0) * 64 + lane] = v0;
            wt[(f + 1) * 64 + lane] = v1;
            wt[(f + 2) * 64 + lane] = v2;
            wt[(f + 3) * 64 + lane] = v3;
        }
    }
    __syncthreads();                               // uniform: no early returns

    // write-out: flat idx = lane + 64*it over [32 f][16 quads];
    // 16 lanes cover one f-plane's 256 B contiguously, dwordx4 each.
    const float4* wt4 = reinterpret_cast<const float4*>(wt);
    const size_t outb = (size_t)b * Ff * G3 + (unsigned)(spatial0 + (wave << 6));
    #pragma unroll
    for (int it = 0; it < 8; ++it) {
        const int idx = lane + (it << 6);
        const int f = idx >> 4, q = idx & 15;
        *reinterpret_cast<float4*>(out + outb + (size_t)f * G3 + (q << 2)) = wt4[idx];
    }
}

// ---------- fallback (atomic path) if ws is too small ----------
__global__ void __launch_bounds__(256) centers_kernel(const float* __restrict__ coords,
                                                      float* __restrict__ centers) {
    const int b = blockIdx.x;
    const int t = threadIdx.x;
    double sx = 0.0, sy = 0.0, sz = 0.0;
    const float* cb = coords + (size_t)b * Nn * 3;
    for (int n = t; n < Nn; n += 256) {
        sx += (double)cb[n * 3 + 0];
        sy += (double)cb[n * 3 + 1];
        sz += (double)cb[n * 3 + 2];
    }
    __shared__ double red[256][3];
    red[t][0] = sx; red[t][1] = sy; red[t][2] = sz;
    __syncthreads();
    for (int s = 128; s > 0; s >>= 1) {
        if (t < s) {
            red[t][0] += red[t + s][0];
            red[t][1] += red[t + s][1];
            red[t][2] += red[t + s][2];
        }
        __syncthreads();
    }
    if (t < 3) centers[b * 3 + t] = (float)(red[0][t] * (1.0 / Nn));
}

__global__ void __launch_bounds__(256) scatter_kernel(const float* __restrict__ coords,
                                                      const float* __restrict__ features,
                                                      const float* __restrict__ W,
                                                      const float* __restrict__ bias,
                                                      const float* __restrict__ centers,
                                                      float* __restrict__ out) {
    __shared__ float Wl[Ff * Ff];
    __shared__ float bl[Ff];
    for (int i = threadIdx.x; i < Ff * Ff; i += 256) Wl[i] = W[i];
    if (threadIdx.x < Ff) bl[threadIdx.x] = bias[threadIdx.x];
    __syncthreads();
    const int atom = blockIdx.x * 256 + threadIdx.x;
    const int b = atom >> 13;
    const float cx = centers[b * 3 + 0];
    const float cy = centers[b * 3 + 1];
    const float cz = centers[b * 3 + 2];
    const float* cp = coords + (size_t)atom * 3;
    const int ix = min(max((int)((cp[0] - cx) + 16.0f), 0), Gg - 1);
    const int iy = min(max((int)((cp[1] - cy) + 16.0f), 0), Gg - 1);
    const int iz = min(max((int)((cp[2] - cz) + 16.0f), 0), Gg - 1);
    const int spatial = ix * (Gg * Gg) + iy * Gg + iz;
    float* outb = out + (size_t)b * Ff * G3 + spatial;
    float ft[Ff];
    const float4* f4 = reinterpret_cast<const float4*>(features + (size_t)atom * Ff);
    #pragma unroll
    for (int q = 0; q < 8; ++q) {
        const float4 v = f4[q];
        ft[4 * q + 0] = v.x; ft[4 * q + 1] = v.y;
        ft[4 * q + 2] = v.z; ft[4 * q + 3] = v.w;
    }
    #pragma unroll 4
    for (int fo = 0; fo < Ff; ++fo) {
        float a2 = bl[fo];
        #pragma unroll
        for (int j = 0; j < Ff; ++j) a2 += Wl[fo * Ff + j] * ft[j];
        atomicAdd(outb + (size_t)fo * G3, a2);
    }
}

extern "C" void kernel_launch(void* const* d_in, const int* in_sizes, int n_in,
                              void* d_out, int out_size, void* d_ws, size_t ws_size,
                              hipStream_t stream) {
    const float* coords   = (const float*)d_in[0];
    const float* features = (const float*)d_in[1];
    const float* W        = (const float*)d_in[2];
    const float* bias     = (const float*)d_in[3];
    float* out = (float*)d_out;

    char* ws = (char*)d_ws;

    if (ws_size < WS_NEED) {
        float* centers = (float*)(ws + WS_CENTERS);
        hipMemsetAsync(d_out, 0, (size_t)out_size * sizeof(float), stream);
        centers_kernel<<<Bb, 256, 0, stream>>>(coords, centers);
        scatter_kernel<<<(NATOM) / 256, 256, 0, stream>>>(coords, features, W, bias, centers, out);
        return;
    }

    unsigned* meta    = (unsigned*)(ws + WS_META);
    unsigned* atomIdx = (unsigned*)(ws + WS_AIDX);

    fused_sort_kernel<<<Bb, 1024, 0, stream>>>(coords, meta, atomIdx);
    gather_kernel<<<Bb * (G3 / 256), 256, 0, stream>>>(meta, atomIdx, features, W, bias, out);
}